// Round 8
// baseline (168.013 us; speedup 1.0000x reference)
//
#include <hip/hip_runtime.h>
#include <math.h>

// out = gelu(rowmean(x@W^T - subtract) + logN) + x
// rowmean(x@W^T)[m] = (1/N) * dot(x[m,:], colsum(W)).  No GEMM needed.
//
// R8 structure: three roofline-clean streaming kernels.
//   A  colsum:   W 64 MB pure read (NT; W never reused)
//   B1 dot:      x 256 MB pure read (plain -> fills the 256 MB L3), g[m] out
//   B2 residual: out = x + g[row]; x re-read hits L3, NT store keeps x resident

typedef float f4 __attribute__((ext_vector_type(4)));

// Kernel A: wsum[k] = sum_n W[n,k] (atomics over row-chunks).
// Last grid.y slice (blockIdx.x==0) also computes submean = mean(subtract).
__global__ __launch_bounds__(256) void colsum_kernel(
    const float* __restrict__ w, const float* __restrict__ sub,
    float* __restrict__ wsum, float* __restrict__ submean,
    int N, int K, int rows_per_block, float invN) {
    if (blockIdx.y == gridDim.y - 1) {
        if (blockIdx.x != 0) return;
        float acc = 0.f;
        for (int i = threadIdx.x; i < N; i += 256) acc += sub[i];
        #pragma unroll
        for (int off = 32; off > 0; off >>= 1) acc += __shfl_down(acc, off, 64);
        __shared__ float sd[4];
        if ((threadIdx.x & 63) == 0) sd[threadIdx.x >> 6] = acc;
        __syncthreads();
        if (threadIdx.x == 0) submean[0] = (sd[0] + sd[1] + sd[2] + sd[3]) * invN;
        return;
    }
    const int K4 = K >> 2;
    const int col4 = blockIdx.x * blockDim.x + threadIdx.x;
    if (col4 >= K4) return;
    const int row0 = blockIdx.y * rows_per_block;
    int row1 = row0 + rows_per_block;
    if (row1 > N) row1 = N;
    const f4* w4 = (const f4*)w;
    f4 acc = (f4)(0.f);
    for (int n = row0; n < row1; ++n) {
        acc += __builtin_nontemporal_load(&w4[(size_t)n * K4 + col4]);
    }
    float* dst = wsum + (size_t)col4 * 4;
    atomicAdd(dst + 0, acc.x);
    atomicAdd(dst + 1, acc.y);
    atomicAdd(dst + 2, acc.z);
    atomicAdd(dst + 3, acc.w);
}

// Kernel B1: pure-read dot pass.  One wave per row; elementwise f4
// accumulator (4 independent FMA chains); nothing held after the loop.
// Plain x loads on purpose: this pass FILLS L3 with x for B2.
__global__ __launch_bounds__(256, 4) void dot_kernel(
    const float* __restrict__ x, const float* __restrict__ wsum,
    const float* __restrict__ submean_p, float* __restrict__ g_out,
    int M, int K, float logN, float invN) {
    const int lane = threadIdx.x & 63;
    const int row = blockIdx.x * 4 + (threadIdx.x >> 6);
    if (row >= M) return;
    const f4* x4 = (const f4*)(x + (size_t)row * K);
    const f4* ws4 = (const f4*)wsum;

    f4 acc = (f4)(0.f);
    #pragma unroll
    for (int j = 0; j < 16; ++j) {
        const int idx = j * 64 + lane;
        acc += x4[idx] * ws4[idx];          // 4 independent chains
    }
    float dot = (acc.x + acc.y) + (acc.z + acc.w);

    #pragma unroll
    for (int off = 1; off < 64; off <<= 1) dot += __shfl_xor(dot, off, 64);

    if (lane == 0) {
        const float c = dot * invN - submean_p[0] + logN;
        const float t = 0.7978845608028654f * fmaf(0.044715f * c, c * c, c);
        g_out[row] = 0.5f * c * (1.f + t / (fabsf(t) + 1.f));
    }
}

// Kernel B2: out = x + g[row].  Copy-like broadcast-add: block per row,
// 4 f4 per thread, no reductions.  x loads plain (L3 hits expected),
// out stores NT (don't evict x from L3).
__global__ __launch_bounds__(256) void residual_kernel(
    const float* __restrict__ x, const float* __restrict__ g,
    float* __restrict__ out, int K4) {
    const int row = blockIdx.x;
    const float gg = g[row];
    const f4* x4 = (const f4*)x + (size_t)row * K4;
    f4* o4 = (f4*)out + (size_t)row * K4;
    #pragma unroll
    for (int i = threadIdx.x; i < K4; i += 256)
        __builtin_nontemporal_store(x4[i] + (f4)(gg), &o4[i]);
}

extern "C" void kernel_launch(void* const* d_in, const int* in_sizes, int n_in,
                              void* d_out, int out_size, void* d_ws, size_t ws_size,
                              hipStream_t stream) {
    const float* x   = (const float*)d_in[0];
    const float* w   = (const float*)d_in[1];
    const float* sub = (const float*)d_in[2];
    float* out = (float*)d_out;

    const int N = in_sizes[2];            // 4096
    const int K = in_sizes[1] / N;        // 4096
    const int M = in_sizes[0] / K;        // 16384

    float* wsum    = (float*)d_ws;        // K floats
    float* submean = wsum + K;            // 1 float
    float* g       = submean + 1;         // M floats

    (void)hipMemsetAsync(d_ws, 0, (size_t)(K + 1) * sizeof(float), stream);

    const int K4 = K / 4;
    const int rows_per_block = 16;
    dim3 gA((K4 + 255) / 256, N / rows_per_block + 1);
    colsum_kernel<<<gA, 256, 0, stream>>>(w, sub, wsum, submean,
                                          N, K, rows_per_block, 1.0f / (float)N);

    dot_kernel<<<M / 4, 256, 0, stream>>>(
        x, wsum, submean, g, M, K, logf((float)N), 1.0f / (float)N);

    residual_kernel<<<M, 256, 0, stream>>>(x, g, out, K4);
}

// Round 9
// 150.975 us; speedup vs baseline: 1.1129x; 1.1129x over previous
//
#include <hip/hip_runtime.h>
#include <math.h>

// out = gelu(rowmean(x@W^T - subtract) + logN) + x
// rowmean(x@W^T)[m] = (1/N) * dot(x[m,:], colsum(W)).  No GEMM needed.
//
// R9: persistent rotating pipeline. Each wave processes a strided list of
// rows; while row r is reduced+stored, row r+stride's loads are in flight.
// Continuous read+write streams (copy-like) with register residency.

typedef float f4 __attribute__((ext_vector_type(4)));

// Kernel A: wsum[k] = sum_n W[n,k] (atomics over row-chunks).
// Last grid.y slice (blockIdx.x==0) also computes submean = mean(subtract).
__global__ __launch_bounds__(256) void colsum_kernel(
    const float* __restrict__ w, const float* __restrict__ sub,
    float* __restrict__ wsum, float* __restrict__ submean,
    int N, int K, int rows_per_block, float invN) {
    if (blockIdx.y == gridDim.y - 1) {
        if (blockIdx.x != 0) return;
        float acc = 0.f;
        for (int i = threadIdx.x; i < N; i += 256) acc += sub[i];
        #pragma unroll
        for (int off = 32; off > 0; off >>= 1) acc += __shfl_down(acc, off, 64);
        __shared__ float sd[4];
        if ((threadIdx.x & 63) == 0) sd[threadIdx.x >> 6] = acc;
        __syncthreads();
        if (threadIdx.x == 0) submean[0] = (sd[0] + sd[1] + sd[2] + sd[3]) * invN;
        return;
    }
    const int K4 = K >> 2;
    const int col4 = blockIdx.x * blockDim.x + threadIdx.x;
    if (col4 >= K4) return;
    const int row0 = blockIdx.y * rows_per_block;
    int row1 = row0 + rows_per_block;
    if (row1 > N) row1 = N;
    const f4* w4 = (const f4*)w;
    f4 acc = (f4)(0.f);
    for (int n = row0; n < row1; ++n) {
        acc += __builtin_nontemporal_load(&w4[(size_t)n * K4 + col4]);
    }
    float* dst = wsum + (size_t)col4 * 4;
    atomicAdd(dst + 0, acc.x);
    atomicAdd(dst + 1, acc.y);
    atomicAdd(dst + 2, acc.z);
    atomicAdd(dst + 3, acc.w);
}

// Kernel B: persistent rotating two-row pipeline, one wave per row.
// wsum lives in LDS (no VMEM companion stream in the dot phase).
__global__ __launch_bounds__(256, 3) void fused_row_kernel(
    const float* __restrict__ x, const float* __restrict__ wsum,
    const float* __restrict__ submean_p, float* __restrict__ out,
    int M, int K, float logN, float invN, int NW) {
    const int lane = threadIdx.x & 63;
    const int wid  = blockIdx.x * 4 + (threadIdx.x >> 6);

    // Stage wsum into LDS once per block (16 KB).
    __shared__ f4 lws[1024];
    const f4* ws4 = (const f4*)wsum;
    for (int i = threadIdx.x; i < (K >> 2); i += 256) lws[i] = ws4[i];
    __syncthreads();

    if (wid >= M) return;
    const float sm = submean_p[0];

    int r = wid;
    f4 xa[16];
    {
        const f4* xr = (const f4*)(x + (size_t)r * K);
        #pragma unroll
        for (int j = 0; j < 16; ++j)
            xa[j] = __builtin_nontemporal_load(&xr[j * 64 + lane]);
    }

    while (true) {
        const int rn = r + NW;
        const bool has_next = rn < M;

        // Issue next row's loads FIRST -- they stay in flight through this
        // row's dot/reduce/store (the pipeline overlap).
        f4 xb[16];
        if (has_next) {
            const f4* xrn = (const f4*)(x + (size_t)rn * K);
            #pragma unroll
            for (int j = 0; j < 16; ++j)
                xb[j] = __builtin_nontemporal_load(&xrn[j * 64 + lane]);
        }

        // dot(xa, wsum) from LDS.  Opaque base index defeats LICM hoisting
        // of the 16 ds_reads out of the row loop (would cost 64 VGPRs).
        int wsbase = 0;
        asm volatile("" : "+v"(wsbase));
        float dot = 0.f;
        #pragma unroll
        for (int j = 0; j < 16; ++j) {
            const f4 ww = lws[wsbase + j * 64 + lane];
            dot = fmaf(xa[j].x, ww.x, fmaf(xa[j].y, ww.y,
                  fmaf(xa[j].z, ww.z, fmaf(xa[j].w, ww.w, dot))));
        }

        #pragma unroll
        for (int off = 1; off < 64; off <<= 1) dot += __shfl_xor(dot, off, 64);

        const float c = dot * invN - sm + logN;
        const float t = 0.7978845608028654f * fmaf(0.044715f * c, c * c, c);
        const float g = 0.5f * c * (1.f + t / (fabsf(t) + 1.f));

        f4* o4 = (f4*)(out + (size_t)r * K);
        #pragma unroll
        for (int j = 0; j < 16; ++j)
            __builtin_nontemporal_store(xa[j] + (f4)(g), &o4[j * 64 + lane]);

        if (!has_next) break;
        #pragma unroll
        for (int j = 0; j < 16; ++j) xa[j] = xb[j];   // rotate
        r = rn;
    }
}

extern "C" void kernel_launch(void* const* d_in, const int* in_sizes, int n_in,
                              void* d_out, int out_size, void* d_ws, size_t ws_size,
                              hipStream_t stream) {
    const float* x   = (const float*)d_in[0];
    const float* w   = (const float*)d_in[1];
    const float* sub = (const float*)d_in[2];
    float* out = (float*)d_out;

    const int N = in_sizes[2];            // 4096
    const int K = in_sizes[1] / N;        // 4096
    const int M = in_sizes[0] / K;        // 16384

    float* wsum    = (float*)d_ws;        // K floats
    float* submean = wsum + K;            // 1 float

    (void)hipMemsetAsync(d_ws, 0, (size_t)(K + 1) * sizeof(float), stream);

    const int K4 = K / 4;
    const int rows_per_block = 16;
    dim3 gA((K4 + 255) / 256, N / rows_per_block + 1);
    colsum_kernel<<<gA, 256, 0, stream>>>(w, sub, wsum, submean,
                                          N, K, rows_per_block, 1.0f / (float)N);

    // 768 blocks = 3 blocks/CU = 12 waves/CU at ~150 VGPR; NW = 3072 waves.
    const int nblocks = 768;
    const int NW = nblocks * 4;
    fused_row_kernel<<<nblocks, 256, 0, stream>>>(
        x, wsum, submean, out, M, K, logf((float)N), 1.0f / (float)N, NW);
}

// Round 10
// 131.261 us; speedup vs baseline: 1.2800x; 1.1502x over previous
//
#include <hip/hip_runtime.h>
#include <math.h>

// out = gelu(rowmean(x@W^T - subtract) + logN) + x
// rowmean(x@W^T)[m] = (1/N) * dot(x[m,:], colsum(W)).  No GEMM needed.
//
// R10 = R3 structure (best: wave-per-row, 16 f4/lane register-resident)
// with two deltas: PLAIN x loads (L2-smoothed read stream, m13-copy-like)
// + NT stores (fillBuffer-like no-allocate write path), and 4 independent
// FMA accumulator chains instead of a 64-deep serial fmaf chain.

typedef float f4 __attribute__((ext_vector_type(4)));

// Kernel A: wsum[k] = sum_n W[n,k] (atomics over row-chunks).
// Last grid.y slice (blockIdx.x==0) also computes submean = mean(subtract).
__global__ __launch_bounds__(256) void colsum_kernel(
    const float* __restrict__ w, const float* __restrict__ sub,
    float* __restrict__ wsum, float* __restrict__ submean,
    int N, int K, int rows_per_block, float invN) {
    if (blockIdx.y == gridDim.y - 1) {
        if (blockIdx.x != 0) return;
        float acc = 0.f;
        for (int i = threadIdx.x; i < N; i += 256) acc += sub[i];
        #pragma unroll
        for (int off = 32; off > 0; off >>= 1) acc += __shfl_down(acc, off, 64);
        __shared__ float sd[4];
        if ((threadIdx.x & 63) == 0) sd[threadIdx.x >> 6] = acc;
        __syncthreads();
        if (threadIdx.x == 0) submean[0] = (sd[0] + sd[1] + sd[2] + sd[3]) * invN;
        return;
    }
    const int K4 = K >> 2;
    const int col4 = blockIdx.x * blockDim.x + threadIdx.x;
    if (col4 >= K4) return;
    const int row0 = blockIdx.y * rows_per_block;
    int row1 = row0 + rows_per_block;
    if (row1 > N) row1 = N;
    const f4* w4 = (const f4*)w;
    f4 acc = (f4)(0.f);
    for (int n = row0; n < row1; ++n) {
        acc += __builtin_nontemporal_load(&w4[(size_t)n * K4 + col4]);
    }
    float* dst = wsum + (size_t)col4 * 4;
    atomicAdd(dst + 0, acc.x);
    atomicAdd(dst + 1, acc.y);
    atomicAdd(dst + 2, acc.z);
    atomicAdd(dst + 3, acc.w);
}

// Kernel B: one WAVE per row, 16 float4/lane register-resident.
// Plain x loads, NT stores, elementwise f4 accumulator (4 indep chains).
__global__ __launch_bounds__(256) void fused_row_kernel(
    const float* __restrict__ x, const float* __restrict__ wsum,
    const float* __restrict__ submean_p, float* __restrict__ out,
    int M, int K, float logN, float invN) {
    const int lane = threadIdx.x & 63;
    const int row = blockIdx.x * 4 + (threadIdx.x >> 6);
    if (row >= M) return;
    const f4* x4 = (const f4*)(x + (size_t)row * K);
    const f4* ws4 = (const f4*)wsum;

    f4 xv[16];
    f4 acc = (f4)(0.f);
    #pragma unroll
    for (int j = 0; j < 16; ++j) {
        const int idx = j * 64 + lane;               // coalesced per wave
        const f4 xx = x4[idx];                       // plain load (L2 path)
        const f4 ww = ws4[idx];                      // L1-resident (16 KB)
        xv[j] = xx;
        acc += xx * ww;                              // 4 independent chains
    }
    float dot = (acc.x + acc.y) + (acc.z + acc.w);

    #pragma unroll
    for (int off = 1; off < 64; off <<= 1) dot += __shfl_xor(dot, off, 64);

    const float c = dot * invN - submean_p[0] + logN;
    const float t = 0.7978845608028654f * fmaf(0.044715f * c, c * c, c);
    const float g = 0.5f * c * (1.f + t / (fabsf(t) + 1.f));

    f4* o4 = (f4*)(out + (size_t)row * K);
    #pragma unroll
    for (int j = 0; j < 16; ++j) {
        const int idx = j * 64 + lane;
        __builtin_nontemporal_store(xv[j] + (f4)(g), &o4[idx]);  // NT store
    }
}

extern "C" void kernel_launch(void* const* d_in, const int* in_sizes, int n_in,
                              void* d_out, int out_size, void* d_ws, size_t ws_size,
                              hipStream_t stream) {
    const float* x   = (const float*)d_in[0];
    const float* w   = (const float*)d_in[1];
    const float* sub = (const float*)d_in[2];
    float* out = (float*)d_out;

    const int N = in_sizes[2];            // 4096
    const int K = in_sizes[1] / N;        // 4096
    const int M = in_sizes[0] / K;        // 16384

    float* wsum    = (float*)d_ws;        // K floats
    float* submean = wsum + K;            // 1 float

    (void)hipMemsetAsync(d_ws, 0, (size_t)(K + 1) * sizeof(float), stream);

    const int K4 = K / 4;
    const int rows_per_block = 16;
    dim3 gA((K4 + 255) / 256, N / rows_per_block + 1);
    colsum_kernel<<<gA, 256, 0, stream>>>(w, sub, wsum, submean,
                                          N, K, rows_per_block, 1.0f / (float)N);

    fused_row_kernel<<<M / 4, 256, 0, stream>>>(
        x, wsum, submean, out, M, K, logf((float)N), 1.0f / (float)N);
}